// Round 12
// baseline (351.646 us; speedup 1.0000x reference)
//
#include <hip/hip_runtime.h>
#include <hip/hip_bf16.h>

#define B_ 4
#define T_ 2048
#define D_ 512
#define H_ 8
#define E_ 32
#define DLAT_ 64
#define DH_ 64
#define M_ (B_*T_)   // 8192 tokens

typedef unsigned short u16;
typedef unsigned int u32;
typedef __bf16 bf16x8 __attribute__((ext_vector_type(8)));
typedef float f32x4 __attribute__((ext_vector_type(4)));

__device__ __forceinline__ float bf2f(u16 u) {
    union { u32 i; float f; } c; c.i = ((u32)u) << 16; return c.f;
}
__device__ __forceinline__ u16 f2bf(float f) { // round-to-nearest-even
    union { float f; u32 i; } c; c.f = f;
    u32 x = c.i; x += 0x7fffu + ((x >> 16) & 1u);
    return (u16)(x >> 16);
}
__device__ __forceinline__ u32 pack2(float a, float b) {
    return (u32)f2bf(a) | ((u32)f2bf(b) << 16);
}

// ---------------------------------------------------------------------------
// Fused prep: 6 weight transposes (fp32 -> bf16, (K,N)->(N,K)) + RoPE table,
// one launch. Flat blockIdx decode; all branches block-uniform.
// ---------------------------------------------------------------------------
__global__ __launch_bounds__(256) void prep_k(
    const float* __restrict__ wq, const float* __restrict__ wkd,
    const float* __restrict__ wku, const float* __restrict__ wo,
    const float* __restrict__ wg, const float* __restrict__ expw,
    u16* __restrict__ wqT, u16* __restrict__ wkdT, u16* __restrict__ wkuT,
    u16* __restrict__ woT, u16* __restrict__ wgT, u16* __restrict__ expT,
    float2* __restrict__ rope)
{
    int b = blockIdx.x;
    if (b >= 8816) {  // RoPE table: tab[t*32+j] = {cos, sin}
        int i = (b - 8816) * 256 + threadIdx.x;
        int tpos = i >> 5, j = i & 31;
        float inv = exp2f(-(float)j * (13.287712379549449f / 32.0f));
        float ang = (float)tpos * inv;
        float sn, cs;
        sincosf(ang, &sn, &cs);
        rope[i] = make_float2(cs, sn);
        return;
    }
    const float* src; u16* dst;
    int R, C, dstStride, dstBatchOff, bx, by, z = 0;
    long srcBatch = 0;
    if (b < 256)      { src = wq;  dst = wqT;  R = 512; C = 512;  dstStride = 512;
                        dstBatchOff = 0; bx = b & 15; by = b >> 4; }
    else if (b < 288) { b -= 256; src = wkd; dst = wkdT; R = 512; C = 64; dstStride = 512;
                        dstBatchOff = 0; bx = b & 1;  by = b >> 1; }
    else if (b < 352) { b -= 288; src = wku; dst = wkuT; R = 64; C = 1024; dstStride = 64;
                        dstBatchOff = 0; bx = b & 31; by = b >> 5; }
    else if (b < 608) { b -= 352; src = wo;  dst = woT;  R = 512; C = 512; dstStride = 512;
                        dstBatchOff = 0; bx = b & 15; by = b >> 4; }
    else if (b < 624) { b -= 608; src = wg;  dst = wgT;  R = 512; C = 32;  dstStride = 512;
                        dstBatchOff = 0; bx = 0;      by = b; }
    else              { b -= 624; src = expw; dst = expT; R = 512; C = 512; dstStride = 16384;
                        dstBatchOff = 512; bx = b & 15; by = (b >> 4) & 15; z = b >> 8;
                        srcBatch = (long)512 * 512; }
    __shared__ float tile[32][33];
    const float* s = src + (long)z * srcBatch;
    const int c0 = bx * 32, r0 = by * 32;
    const int tx = threadIdx.x & 31, ty = threadIdx.x >> 5;  // 32 x 8
#pragma unroll
    for (int i = 0; i < 32; i += 8) {
        int r = r0 + ty + i, c = c0 + tx;
        if (r < R && c < C) tile[ty + i][tx] = s[(long)r * C + c];
    }
    __syncthreads();
#pragma unroll
    for (int i = 0; i < 32; i += 8) {
        int c = c0 + ty + i, r = r0 + tx;
        if (r < R && c < C)
            dst[(long)c * dstStride + (long)z * dstBatchOff + r] = f2bf(tile[tx][ty + i]);
    }
}

// ---------------------------------------------------------------------------
// RMSNorm: one block (256 thr) per row of 512. Optional fp32 and bf16 outputs.
// ---------------------------------------------------------------------------
__global__ __launch_bounds__(256) void rmsnorm_k(
    const float* __restrict__ x, const float* __restrict__ gamma,
    float* __restrict__ of, u16* __restrict__ ob)
{
    const size_t row = blockIdx.x;
    const int t = threadIdx.x;
    const float* xr = x + row * D_;
    float2 v = *(const float2*)(xr + 2 * t);
    float ss = v.x * v.x + v.y * v.y;
#pragma unroll
    for (int off = 1; off < 64; off <<= 1) ss += __shfl_xor(ss, off, 64);
    __shared__ float wsum[4];
    if ((t & 63) == 0) wsum[t >> 6] = ss;
    __syncthreads();
    float tot = wsum[0] + wsum[1] + wsum[2] + wsum[3];
    float inv = rsqrtf(tot * (1.0f / D_) + 1e-6f);
    float o0 = v.x * inv * gamma[2 * t];
    float o1 = v.y * inv * gamma[2 * t + 1];
    if (of) *(float2*)(of + row * D_ + 2 * t) = make_float2(o0, o1);
    if (ob) *(u32*)(ob + row * D_ + 2 * t) = pack2(o0, o1);
}

// ---------------------------------------------------------------------------
// 8-wave GEMM: 128x128 tile, BK=64, 512 thr = 8 waves (2 row-halves x 4
// col-quarters; per-wave 64x32 = acc[4][2]). Reg-staged LDS. Used for the
// dense projections (wq / kv / wo).
// ---------------------------------------------------------------------------
__global__ __launch_bounds__(512, 4) void gemm8w(
    const u16* __restrict__ A, const u16* __restrict__ Bt,
    const float* __restrict__ bias, const float* __restrict__ resid,
    float* __restrict__ outF, u16* __restrict__ outB, int Ndim, int strideA, int K)
{
    __shared__ __align__(16) u16 lA[128][72];  // +8 pad (144B rows)
    __shared__ __align__(16) u16 lB[128][72];
    const int t = threadIdx.x;
    const int lane = t & 63, wid = t >> 6;
    const int wr = wid >> 2, wc = wid & 3;
    const int rowBase = blockIdx.x * 128;
    const int colBase = blockIdx.y * 128;
    const int srow = t >> 3;        // 0..63
    const int scol = (t & 7) * 8;   // 0..56
    const int l15 = lane & 15;
    const int kreg = (lane >> 4) * 8;

    f32x4 acc[4][2] = {};

    for (int kb = 0; kb < K; kb += 64) {
#pragma unroll
        for (int i = 0; i < 2; ++i) {
            int r = srow + 64 * i;
            *(int4*)(&lA[r][scol]) =
                *(const int4*)(A + (size_t)(rowBase + r) * strideA + kb + scol);
            *(int4*)(&lB[r][scol]) =
                *(const int4*)(Bt + (size_t)(colBase + r) * K + kb + scol);
        }
        __syncthreads();
#pragma unroll
        for (int kk = 0; kk < 64; kk += 32) {
            const int ko = kk + kreg;
            bf16x8 af[4], bfr[2];
#pragma unroll
            for (int mi = 0; mi < 4; ++mi)
                af[mi] = *(const bf16x8*)(&lA[wr * 64 + mi * 16 + l15][ko]);
#pragma unroll
            for (int ni = 0; ni < 2; ++ni)
                bfr[ni] = *(const bf16x8*)(&lB[wc * 32 + ni * 16 + l15][ko]);
#pragma unroll
            for (int mi = 0; mi < 4; ++mi)
#pragma unroll
                for (int ni = 0; ni < 2; ++ni)
                    acc[mi][ni] = __builtin_amdgcn_mfma_f32_16x16x32_bf16(
                        af[mi], bfr[ni], acc[mi][ni], 0, 0, 0);
        }
        __syncthreads();
    }
#pragma unroll
    for (int mi = 0; mi < 4; ++mi)
#pragma unroll
        for (int ni = 0; ni < 2; ++ni)
#pragma unroll
            for (int r = 0; r < 4; ++r) {
                int grow = rowBase + wr * 64 + mi * 16 + (lane >> 4) * 4 + r;
                int gcol = colBase + wc * 32 + ni * 16 + l15;
                float v = acc[mi][ni][r];
                if (bias)  v += bias[gcol];
                if (resid) v += resid[(size_t)grow * Ndim + gcol];
                if (outF)  outF[(size_t)grow * Ndim + gcol] = v;
                if (outB)  outB[(size_t)grow * Ndim + gcol] = f2bf(v);
            }
}

// ---------------------------------------------------------------------------
// MoE GEMM with T14 async-STAGE split on a SINGLE LDS buffer: BM=256 x BN=128,
// BK=64, 512 thr = 8 waves (4 row x 2 col; per-wave 64x64 = acc[4][4]).
// Per K-step: foldwrite(t) -> barrier -> issue(t+1) [loads fly during compute]
// -> compute(t) -> barrier. Gate folded into A at the reg->LDS write (native
// __bf16, m240). LDS 55 KB -> 2 blocks/CU preserved; +28 regs held (ra/rb/g,
// ~88-96 total <= 128 cap). Split-K=4 over blockIdx.z (8 experts each);
// z==0 writes fp32 partial + resid (x1); z=1..3 write bf16 partials.
// ---------------------------------------------------------------------------
#define KPS_ 4096
__global__ __launch_bounds__(512, 4) void moe256(
    const u16* __restrict__ A, const u16* __restrict__ Bt,
    const float* __restrict__ gate, const float* __restrict__ resid,
    float* __restrict__ partF, u16* __restrict__ partB)
{
    __shared__ __align__(16) u16 lA[256][72];  // 36864 B
    __shared__ __align__(16) u16 lB[128][72];  // 18432 B
    const int t = threadIdx.x;
    const int lane = t & 63, wid = t >> 6;
    const int wr = wid >> 1, wc = wid & 1;      // wave -> 64-row, 64-col quadrant
    const int rowBase = blockIdx.x * 256;
    const int colBase = blockIdx.y * 128;
    const int z = blockIdx.z;
    const int eBase = z * (KPS_ / 512);         // 8 experts per split
    float* outF = (z == 0) ? partF : nullptr;
    u16* outB = (z == 0) ? nullptr : partB + (size_t)(z - 1) * M_ * D_;
    const int srow = t >> 3;        // 0..63
    const int scol = (t & 7) * 8;   // 0..56
    const int l15 = lane & 15;
    const int kreg = (lane >> 4) * 8;
    const int NT = KPS_ / 64;       // 64 K-step tiles

    f32x4 acc[4][4] = {};
    int4 ra[4], rb[2];
    float g[4];

    auto issue = [&](int tt) {   // global loads for tile tt -> regs (in flight)
        const int e = eBase + (tt >> 3);
        const int akb = (tt & 7) * 64;
        const int kb = e * 512 + akb;
#pragma unroll
        for (int i = 0; i < 4; ++i) {
            int r = rowBase + srow + 64 * i;
            ra[i] = *(const int4*)(A + (size_t)r * 512 + akb + scol);
            g[i] = gate[(size_t)r * E_ + e];
        }
#pragma unroll
        for (int i = 0; i < 2; ++i)
            rb[i] = *(const int4*)(Bt + (size_t)(colBase + srow + 64 * i) * (E_ * 512)
                                   + kb + scol);
    };
    auto foldwrite = [&]() {  // vmcnt-wait (first use) + gate-fold + LDS write
#pragma unroll
        for (int i = 0; i < 4; ++i) {
            bf16x8 raw = *(bf16x8*)&ra[i];
            bf16x8 o;
#pragma unroll
            for (int j = 0; j < 8; ++j)
                o[j] = (__bf16)((float)raw[j] * g[i]);
            *(bf16x8*)(&lA[srow + 64 * i][scol]) = o;
        }
#pragma unroll
        for (int i = 0; i < 2; ++i)
            *(int4*)(&lB[srow + 64 * i][scol]) = rb[i];
    };
    auto compute = [&]() {
#pragma unroll
        for (int kk = 0; kk < 64; kk += 32) {
            const int ko = kk + kreg;
            bf16x8 af[4], bfr[4];
#pragma unroll
            for (int mi = 0; mi < 4; ++mi)
                af[mi] = *(const bf16x8*)(&lA[wr * 64 + mi * 16 + l15][ko]);
#pragma unroll
            for (int ni = 0; ni < 4; ++ni)
                bfr[ni] = *(const bf16x8*)(&lB[wc * 64 + ni * 16 + l15][ko]);
#pragma unroll
            for (int mi = 0; mi < 4; ++mi)
#pragma unroll
                for (int ni = 0; ni < 4; ++ni)
                    acc[mi][ni] = __builtin_amdgcn_mfma_f32_16x16x32_bf16(
                        af[mi], bfr[ni], acc[mi][ni], 0, 0, 0);
        }
    };

    issue(0);
#pragma unroll 1
    for (int tt = 0; tt < NT; ++tt) {
        foldwrite();                 // consume ra/rb/g for tile tt
        __syncthreads();             // LDS writes visible to all waves
        if (tt + 1 < NT) issue(tt + 1);  // next-tile loads fly during compute
        compute();
        __syncthreads();             // all LDS reads done before next foldwrite
    }

    // epilogue: C/D layout col=lane&15, row=(lane>>4)*4+reg  [m89-verified]
#pragma unroll
    for (int mi = 0; mi < 4; ++mi)
#pragma unroll
        for (int ni = 0; ni < 4; ++ni)
#pragma unroll
            for (int r = 0; r < 4; ++r) {
                int grow = rowBase + wr * 64 + mi * 16 + (lane >> 4) * 4 + r;
                int gcol = colBase + wc * 64 + ni * 16 + l15;
                float v = acc[mi][ni][r];
                if (outF) {
                    v += resid[(size_t)grow * D_ + gcol];
                    outF[(size_t)grow * D_ + gcol] = v;
                } else {
                    outB[(size_t)grow * D_ + gcol] = f2bf(v);
                }
            }
}

// ---------------------------------------------------------------------------
// Fallback GEMM (reg-staged, 128x64 tile, 256 thr) for N=64 (kd).
// ---------------------------------------------------------------------------
__global__ __launch_bounds__(256) void gemm_bt(
    const u16* __restrict__ A, const u16* __restrict__ Bt,
    const float* __restrict__ bias, float* __restrict__ outF,
    u16* __restrict__ outB, int Ndim, int K)
{
    __shared__ __align__(16) u16 lA[128][72];
    __shared__ __align__(16) u16 lB[64][72];
    const int t = threadIdx.x;
    const int lane = t & 63, wid = t >> 6;
    const int rowBase = blockIdx.x * 128;
    const int colBase = blockIdx.y * 64;
    const int srow = t >> 3;
    const int skb = (t & 7) * 8;
    const int l15 = lane & 15;
    const int kreg = (lane >> 4) * 8;

    f32x4 accT[2][4] = {};

    for (int kb = 0; kb < K; kb += 64) {
#pragma unroll
        for (int i = 0; i < 4; ++i) {
            int r = srow + 32 * i;
            size_t grow = (size_t)(rowBase + r);
            *(int4*)(&lA[r][skb]) = *(const int4*)(A + grow * (size_t)K + kb + skb);
        }
#pragma unroll
        for (int i = 0; i < 2; ++i) {
            int n = srow + 32 * i;
            int gn = colBase + n;
            int4 v = {0, 0, 0, 0};
            if (gn < Ndim) v = *(const int4*)(Bt + (size_t)gn * K + kb + skb);
            *(int4*)(&lB[n][skb]) = v;
        }
        __syncthreads();
#pragma unroll
        for (int kk = 0; kk < 64; kk += 32) {
            const int ko = kk + kreg;
            bf16x8 af[2], bfr[4];
            af[0] = *(const bf16x8*)(&lA[wid * 32 + l15][ko]);
            af[1] = *(const bf16x8*)(&lA[wid * 32 + 16 + l15][ko]);
#pragma unroll
            for (int ni = 0; ni < 4; ++ni)
                bfr[ni] = *(const bf16x8*)(&lB[ni * 16 + l15][ko]);
#pragma unroll
            for (int mi = 0; mi < 2; ++mi)
#pragma unroll
                for (int ni = 0; ni < 4; ++ni)
                    accT[mi][ni] = __builtin_amdgcn_mfma_f32_16x16x32_bf16(
                        af[mi], bfr[ni], accT[mi][ni], 0, 0, 0);
        }
        __syncthreads();
    }
#pragma unroll
    for (int mi = 0; mi < 2; ++mi)
#pragma unroll
        for (int ni = 0; ni < 4; ++ni)
#pragma unroll
            for (int r = 0; r < 4; ++r) {
                int grow = rowBase + wid * 32 + mi * 16 + (lane >> 4) * 4 + r;
                int gcol = colBase + ni * 16 + l15;
                if (gcol < Ndim) {
                    float v = accT[mi][ni][r];
                    if (bias)  v += bias[gcol];
                    if (outF)  outF[(size_t)grow * Ndim + gcol] = v;
                    if (outB)  outB[(size_t)grow * Ndim + gcol] = f2bf(v);
                }
            }
}

// ---------------------------------------------------------------------------
// Gate fused: logits = h2 @ wgT + bg (MFMA, N=32), softmax over 32 in-register.
// ---------------------------------------------------------------------------
__global__ __launch_bounds__(256) void gatefused_k(
    const u16* __restrict__ A, const u16* __restrict__ Bt,
    const float* __restrict__ bg, float* __restrict__ gate)
{
    __shared__ __align__(16) u16 lA[128][72];
    __shared__ __align__(16) u16 lB[32][72];
    const int t = threadIdx.x;
    const int lane = t & 63, wid = t >> 6;
    const int rowBase = blockIdx.x * 128;
    const int srow = t >> 3;        // 0..31
    const int skb = (t & 7) * 8;
    const int l15 = lane & 15;
    const int kreg = (lane >> 4) * 8;

    f32x4 accT[2][2] = {};

    for (int kb = 0; kb < 512; kb += 64) {
#pragma unroll
        for (int i = 0; i < 4; ++i) {
            int r = srow + 32 * i;
            *(int4*)(&lA[r][skb]) =
                *(const int4*)(A + (size_t)(rowBase + r) * 512 + kb + skb);
        }
        *(int4*)(&lB[srow][skb]) = *(const int4*)(Bt + (size_t)srow * 512 + kb + skb);
        __syncthreads();
#pragma unroll
        for (int kk = 0; kk < 64; kk += 32) {
            const int ko = kk + kreg;
            bf16x8 af[2], bfr[2];
            af[0] = *(const bf16x8*)(&lA[wid * 32 + l15][ko]);
            af[1] = *(const bf16x8*)(&lA[wid * 32 + 16 + l15][ko]);
#pragma unroll
            for (int ni = 0; ni < 2; ++ni)
                bfr[ni] = *(const bf16x8*)(&lB[ni * 16 + l15][ko]);
#pragma unroll
            for (int mi = 0; mi < 2; ++mi)
#pragma unroll
                for (int ni = 0; ni < 2; ++ni)
                    accT[mi][ni] = __builtin_amdgcn_mfma_f32_16x16x32_bf16(
                        af[mi], bfr[ni], accT[mi][ni], 0, 0, 0);
        }
        __syncthreads();
    }
#pragma unroll
    for (int mi = 0; mi < 2; ++mi)
#pragma unroll
        for (int r = 0; r < 4; ++r) {
            float v0 = accT[mi][0][r] + bg[l15];
            float v1 = accT[mi][1][r] + bg[16 + l15];
            float m = fmaxf(v0, v1);
#pragma unroll
            for (int off = 1; off < 16; off <<= 1) m = fmaxf(m, __shfl_xor(m, off, 64));
            float p0 = __expf(v0 - m), p1 = __expf(v1 - m);
            float den = p0 + p1;
#pragma unroll
            for (int off = 1; off < 16; off <<= 1) den += __shfl_xor(den, off, 64);
            float rinv = 1.0f / den;
            int grow = rowBase + wid * 32 + mi * 16 + (lane >> 4) * 4 + r;
            gate[(size_t)grow * E_ + l15] = p0 * rinv;
            gate[(size_t)grow * E_ + 16 + l15] = p1 * rinv;
        }
}

// ---------------------------------------------------------------------------
// out = pF + bf(p1) + bf(p2) + bf(p3)   (pF fp32 already includes x1)
// ---------------------------------------------------------------------------
__global__ __launch_bounds__(256) void reduceP_k(
    const float* __restrict__ pf, const u16* __restrict__ pb,
    float* __restrict__ o, int n4)
{
    int i = blockIdx.x * 256 + threadIdx.x;
    const int stride = gridDim.x * 256;
    for (; i < n4; i += stride) {
        float4 v = ((const float4*)pf)[i];
#pragma unroll
        for (int s = 0; s < 3; ++s) {
            ushort4 u = ((const ushort4*)pb)[i + s * n4];
            v.x += bf2f(u.x); v.y += bf2f(u.y);
            v.z += bf2f(u.z); v.w += bf2f(u.w);
        }
        ((float4*)o)[i] = v;
    }
}

// ---------------------------------------------------------------------------
// Per-token attention across heads (bf16 q/kv): RoPE (table), 8x8 scores,
// softmax, PV. 4 tokens per 256-thr block, one wave per token.
// ---------------------------------------------------------------------------
__global__ __launch_bounds__(256) void attn_k(
    const u16* __restrict__ q, const u16* __restrict__ kv,
    const float2* __restrict__ rope, u16* __restrict__ out)
{
    const int wv = threadIdx.x >> 6;            // 0..3: token slot
    const int tok = blockIdx.x * 4 + wv;
    const int tpos = tok & (T_ - 1);
    const int l = threadIdx.x & 63;
    __shared__ float sq[4][8][65], sk[4][8][65], sv[4][8][65];
    __shared__ float satt[4][8][9];
    const int h = l >> 3;
    const int j0 = (l & 7) * 4;
    const u16* qr = q + (size_t)tok * 512;
    const u16* kr = kv + (size_t)tok * 1024;
#pragma unroll
    for (int jj = 0; jj < 4; ++jj) {
        int j = j0 + jj;
        float2 cssn = rope[tpos * 32 + j];
        float cs = cssn.x, sn = cssn.y;
        float q1 = bf2f(qr[h * 64 + j]), q2 = bf2f(qr[h * 64 + 32 + j]);
        sq[wv][h][j] = q1 * cs - q2 * sn;
        sq[wv][h][j + 32] = q1 * sn + q2 * cs;
        float k1 = bf2f(kr[h * 128 + j]), k2 = bf2f(kr[h * 128 + 32 + j]);
        sk[wv][h][j] = k1 * cs - k2 * sn;
        sk[wv][h][j + 32] = k1 * sn + k2 * cs;
        sv[wv][h][j] = bf2f(kr[h * 128 + 64 + j]);
        sv[wv][h][j + 32] = bf2f(kr[h * 128 + 96 + j]);
    }
    __syncthreads();
    const int g = l & 7;
    float s = 0.f;
#pragma unroll 8
    for (int c = 0; c < 64; ++c) s += sq[wv][h][c] * sk[wv][g][c];
    s *= 0.125f;
    float m = s;
#pragma unroll
    for (int off = 4; off; off >>= 1) m = fmaxf(m, __shfl_xor(m, off, 8));
    float p = __expf(s - m);
    float den = p;
#pragma unroll
    for (int off = 4; off; off >>= 1) den += __shfl_xor(den, off, 8);
    satt[wv][h][g] = p / den;
    __syncthreads();
    const int c8 = (l & 7) * 8;
    float o[8] = {};
#pragma unroll
    for (int gg = 0; gg < 8; ++gg) {
        float a = satt[wv][h][gg];
#pragma unroll
        for (int i = 0; i < 8; ++i) o[i] += a * sv[wv][gg][c8 + i];
    }
    int4 pk;
    pk.x = pack2(o[0], o[1]); pk.y = pack2(o[2], o[3]);
    pk.z = pack2(o[4], o[5]); pk.w = pack2(o[6], o[7]);
    *(int4*)(out + (size_t)tok * 512 + h * 64 + c8) = pk;
}

// ---------------------------------------------------------------------------
extern "C" void kernel_launch(void* const* d_in, const int* in_sizes, int n_in,
                              void* d_out, int out_size, void* d_ws, size_t ws_size,
                              hipStream_t stream)
{
    const float* x      = (const float*)d_in[0];
    const float* gamma1 = (const float*)d_in[1];
    const float* gamma2 = (const float*)d_in[2];
    const float* wq     = (const float*)d_in[3];
    const float* bq     = (const float*)d_in[4];
    const float* wkd    = (const float*)d_in[5];
    const float* bkd    = (const float*)d_in[6];
    const float* wku    = (const float*)d_in[7];
    const float* bku    = (const float*)d_in[8];
    const float* wo     = (const float*)d_in[9];
    const float* bo     = (const float*)d_in[10];
    const float* wg     = (const float*)d_in[11];
    const float* bg     = (const float*)d_in[12];
    const float* expw   = (const float*)d_in[13];

    char* w = (char*)d_ws;
    size_t off = 0;
    auto alloc = [&](size_t bytes) -> void* {
        void* p = w + off; off += (bytes + 255) & ~(size_t)255; return p;
    };
    u16*   h_b    = (u16*)alloc((size_t)M_ * D_ * 2);
    u16*   kd_b   = (u16*)alloc((size_t)M_ * DLAT_ * 2);
    u16*   at_b   = (u16*)alloc((size_t)M_ * D_ * 2);
    u16*   h2_b   = (u16*)alloc((size_t)M_ * D_ * 2);
    u16*   q_b    = (u16*)alloc((size_t)M_ * D_ * 2);
    u16*   kv_b   = (u16*)alloc((size_t)M_ * 2 * D_ * 2);
    float* partF  = (float*)alloc((size_t)M_ * D_ * 4);       // z=0 fp32 (+x1)
    u16*   partB  = (u16*)alloc((size_t)3 * M_ * D_ * 2);     // z=1..3 bf16
    float* x1_f   = (float*)alloc((size_t)M_ * D_ * 4);
    float* gate_f = (float*)alloc((size_t)M_ * E_ * 4);
    float2* rope_t = (float2*)alloc((size_t)T_ * 32 * 8);
    u16*   wqT    = (u16*)alloc((size_t)D_ * D_ * 2);
    u16*   wkdT   = (u16*)alloc((size_t)D_ * DLAT_ * 2);
    u16*   wkuT   = (u16*)alloc((size_t)DLAT_ * 2 * D_ * 2);
    u16*   woT    = (u16*)alloc((size_t)D_ * D_ * 2);
    u16*   wgT    = (u16*)alloc((size_t)D_ * E_ * 2);
    u16*   expT   = (u16*)alloc((size_t)E_ * D_ * D_ * 2);
    (void)ws_size; (void)in_sizes; (void)n_in; (void)out_size;

    // fused prep: all weight transposes + rope table (one launch, 9072 blocks)
    prep_k<<<9072, 256, 0, stream>>>(wq, wkd, wku, wo, wg, expw,
                                     wqT, wkdT, wkuT, woT, wgT, expT, rope_t);
    // h = rmsnorm(x, gamma1)  (bf16 only)
    rmsnorm_k<<<M_, 256, 0, stream>>>(x, gamma1, nullptr, h_b);
    // q = h @ wq + bq (bf16 out)
    gemm8w<<<dim3(64, 4), 512, 0, stream>>>(h_b, wqT, bq, nullptr, nullptr, q_b,
                                            512, 512, 512);
    // kd = h @ wkd + bkd (bf16 out)  -- N=64, fallback kernel
    gemm_bt<<<dim3(64, 1), 256, 0, stream>>>(h_b, wkdT, bkd, nullptr, kd_b, 64, 512);
    // kv = kd @ wku + bku (bf16 out)  -- K=64, single K-step
    gemm8w<<<dim3(64, 8), 512, 0, stream>>>(kd_b, wkuT, bku, nullptr, nullptr, kv_b,
                                            1024, 64, 64);
    // attention (rope + softmax over heads + PV), 4 tokens/block
    attn_k<<<M_ / 4, 256, 0, stream>>>(q_b, kv_b, rope_t, at_b);
    // x1 = x + attnout @ wo + bo (fp32 out)
    gemm8w<<<dim3(64, 4), 512, 0, stream>>>(at_b, woT, bo, x, x1_f, nullptr,
                                            512, 512, 512);
    // h2 = rmsnorm(x1, gamma2) (bf16 only)
    rmsnorm_k<<<M_, 256, 0, stream>>>(x1_f, gamma2, nullptr, h2_b);
    // gate = softmax(h2 @ wg + bg)  -- MFMA GEMM + fused in-register softmax
    gatefused_k<<<dim3(64, 1), 256, 0, stream>>>(h2_b, wgT, bg, gate_f);
    // moe partials: z=0 fp32 (+x1 resid), z=1..3 bf16
    moe256<<<dim3(32, 4, 4), 512, 0, stream>>>(h2_b, expT, gate_f, x1_f,
                                               partF, partB);
    // out = partF + sum of 3 bf16 partials
    reduceP_k<<<2048, 256, 0, stream>>>(partF, partB, (float*)d_out, M_ * D_ / 4);
}

// Round 13
// 323.594 us; speedup vs baseline: 1.0867x; 1.0867x over previous
//
#include <hip/hip_runtime.h>
#include <hip/hip_bf16.h>

#define B_ 4
#define T_ 2048
#define D_ 512
#define H_ 8
#define E_ 32
#define DLAT_ 64
#define DH_ 64
#define M_ (B_*T_)   // 8192 tokens

typedef unsigned short u16;
typedef unsigned int u32;
typedef __bf16 bf16x8 __attribute__((ext_vector_type(8)));
typedef float f32x4 __attribute__((ext_vector_type(4)));

__device__ __forceinline__ float bf2f(u16 u) {
    union { u32 i; float f; } c; c.i = ((u32)u) << 16; return c.f;
}
__device__ __forceinline__ u16 f2bf(float f) { // round-to-nearest-even
    union { float f; u32 i; } c; c.f = f;
    u32 x = c.i; x += 0x7fffu + ((x >> 16) & 1u);
    return (u16)(x >> 16);
}
__device__ __forceinline__ u32 pack2(float a, float b) {
    return (u32)f2bf(a) | ((u32)f2bf(b) << 16);
}

// ---------------------------------------------------------------------------
// Fused prep: 6 weight transposes (fp32 -> bf16, (K,N)->(N,K)) + RoPE table,
// one launch. Flat blockIdx decode; all branches block-uniform.
// ---------------------------------------------------------------------------
__global__ __launch_bounds__(256) void prep_k(
    const float* __restrict__ wq, const float* __restrict__ wkd,
    const float* __restrict__ wku, const float* __restrict__ wo,
    const float* __restrict__ wg, const float* __restrict__ expw,
    u16* __restrict__ wqT, u16* __restrict__ wkdT, u16* __restrict__ wkuT,
    u16* __restrict__ woT, u16* __restrict__ wgT, u16* __restrict__ expT,
    float2* __restrict__ rope)
{
    int b = blockIdx.x;
    if (b >= 8816) {  // RoPE table: tab[t*32+j] = {cos, sin}
        int i = (b - 8816) * 256 + threadIdx.x;
        int tpos = i >> 5, j = i & 31;
        float inv = exp2f(-(float)j * (13.287712379549449f / 32.0f));
        float ang = (float)tpos * inv;
        float sn, cs;
        sincosf(ang, &sn, &cs);
        rope[i] = make_float2(cs, sn);
        return;
    }
    const float* src; u16* dst;
    int R, C, dstStride, dstBatchOff, bx, by, z = 0;
    long srcBatch = 0;
    if (b < 256)      { src = wq;  dst = wqT;  R = 512; C = 512;  dstStride = 512;
                        dstBatchOff = 0; bx = b & 15; by = b >> 4; }
    else if (b < 288) { b -= 256; src = wkd; dst = wkdT; R = 512; C = 64; dstStride = 512;
                        dstBatchOff = 0; bx = b & 1;  by = b >> 1; }
    else if (b < 352) { b -= 288; src = wku; dst = wkuT; R = 64; C = 1024; dstStride = 64;
                        dstBatchOff = 0; bx = b & 31; by = b >> 5; }
    else if (b < 608) { b -= 352; src = wo;  dst = woT;  R = 512; C = 512; dstStride = 512;
                        dstBatchOff = 0; bx = b & 15; by = b >> 4; }
    else if (b < 624) { b -= 608; src = wg;  dst = wgT;  R = 512; C = 32;  dstStride = 512;
                        dstBatchOff = 0; bx = 0;      by = b; }
    else              { b -= 624; src = expw; dst = expT; R = 512; C = 512; dstStride = 16384;
                        dstBatchOff = 512; bx = b & 15; by = (b >> 4) & 15; z = b >> 8;
                        srcBatch = (long)512 * 512; }
    __shared__ float tile[32][33];
    const float* s = src + (long)z * srcBatch;
    const int c0 = bx * 32, r0 = by * 32;
    const int tx = threadIdx.x & 31, ty = threadIdx.x >> 5;  // 32 x 8
#pragma unroll
    for (int i = 0; i < 32; i += 8) {
        int r = r0 + ty + i, c = c0 + tx;
        if (r < R && c < C) tile[ty + i][tx] = s[(long)r * C + c];
    }
    __syncthreads();
#pragma unroll
    for (int i = 0; i < 32; i += 8) {
        int c = c0 + ty + i, r = r0 + tx;
        if (r < R && c < C)
            dst[(long)c * dstStride + (long)z * dstBatchOff + r] = f2bf(tile[tx][ty + i]);
    }
}

// ---------------------------------------------------------------------------
// RMSNorm: one block (256 thr) per row of 512. Optional fp32 and bf16 outputs.
// ---------------------------------------------------------------------------
__global__ __launch_bounds__(256) void rmsnorm_k(
    const float* __restrict__ x, const float* __restrict__ gamma,
    float* __restrict__ of, u16* __restrict__ ob)
{
    const size_t row = blockIdx.x;
    const int t = threadIdx.x;
    const float* xr = x + row * D_;
    float2 v = *(const float2*)(xr + 2 * t);
    float ss = v.x * v.x + v.y * v.y;
#pragma unroll
    for (int off = 1; off < 64; off <<= 1) ss += __shfl_xor(ss, off, 64);
    __shared__ float wsum[4];
    if ((t & 63) == 0) wsum[t >> 6] = ss;
    __syncthreads();
    float tot = wsum[0] + wsum[1] + wsum[2] + wsum[3];
    float inv = rsqrtf(tot * (1.0f / D_) + 1e-6f);
    float o0 = v.x * inv * gamma[2 * t];
    float o1 = v.y * inv * gamma[2 * t + 1];
    if (of) *(float2*)(of + row * D_ + 2 * t) = make_float2(o0, o1);
    if (ob) *(u32*)(ob + row * D_ + 2 * t) = pack2(o0, o1);
}

// ---------------------------------------------------------------------------
// 8-wave GEMM: 128x128 tile, BK=64, 512 thr = 8 waves (2 row-halves x 4
// col-quarters; per-wave 64x32 = acc[4][2]). Reg-staged LDS. Used for the
// dense projections (wq / kv / wo).
// ---------------------------------------------------------------------------
__global__ __launch_bounds__(512, 4) void gemm8w(
    const u16* __restrict__ A, const u16* __restrict__ Bt,
    const float* __restrict__ bias, const float* __restrict__ resid,
    float* __restrict__ outF, u16* __restrict__ outB, int Ndim, int strideA, int K)
{
    __shared__ __align__(16) u16 lA[128][72];  // +8 pad (144B rows)
    __shared__ __align__(16) u16 lB[128][72];
    const int t = threadIdx.x;
    const int lane = t & 63, wid = t >> 6;
    const int wr = wid >> 2, wc = wid & 3;
    const int rowBase = blockIdx.x * 128;
    const int colBase = blockIdx.y * 128;
    const int srow = t >> 3;        // 0..63
    const int scol = (t & 7) * 8;   // 0..56
    const int l15 = lane & 15;
    const int kreg = (lane >> 4) * 8;

    f32x4 acc[4][2] = {};

    for (int kb = 0; kb < K; kb += 64) {
#pragma unroll
        for (int i = 0; i < 2; ++i) {
            int r = srow + 64 * i;
            *(int4*)(&lA[r][scol]) =
                *(const int4*)(A + (size_t)(rowBase + r) * strideA + kb + scol);
            *(int4*)(&lB[r][scol]) =
                *(const int4*)(Bt + (size_t)(colBase + r) * K + kb + scol);
        }
        __syncthreads();
#pragma unroll
        for (int kk = 0; kk < 64; kk += 32) {
            const int ko = kk + kreg;
            bf16x8 af[4], bfr[2];
#pragma unroll
            for (int mi = 0; mi < 4; ++mi)
                af[mi] = *(const bf16x8*)(&lA[wr * 64 + mi * 16 + l15][ko]);
#pragma unroll
            for (int ni = 0; ni < 2; ++ni)
                bfr[ni] = *(const bf16x8*)(&lB[wc * 32 + ni * 16 + l15][ko]);
#pragma unroll
            for (int mi = 0; mi < 4; ++mi)
#pragma unroll
                for (int ni = 0; ni < 2; ++ni)
                    acc[mi][ni] = __builtin_amdgcn_mfma_f32_16x16x32_bf16(
                        af[mi], bfr[ni], acc[mi][ni], 0, 0, 0);
        }
        __syncthreads();
    }
#pragma unroll
    for (int mi = 0; mi < 4; ++mi)
#pragma unroll
        for (int ni = 0; ni < 2; ++ni)
#pragma unroll
            for (int r = 0; r < 4; ++r) {
                int grow = rowBase + wr * 64 + mi * 16 + (lane >> 4) * 4 + r;
                int gcol = colBase + wc * 32 + ni * 16 + l15;
                float v = acc[mi][ni][r];
                if (bias)  v += bias[gcol];
                if (resid) v += resid[(size_t)grow * Ndim + gcol];
                if (outF)  outF[(size_t)grow * Ndim + gcol] = v;
                if (outB)  outB[(size_t)grow * Ndim + gcol] = f2bf(v);
            }
}

// ---------------------------------------------------------------------------
// MoE GEMM (round-8/10/11 proven structure): BM=256 x BN=128, BK=64, 512 thr
// = 8 waves (4 row x 2 col; per-wave 64x64 = acc[4][4]). Gate folded into A
// during staging via native __bf16 (m240). Gate loads hoisted per expert.
// Split-K=4 over blockIdx.z (KPS=4096 = 8 experts); z==0 writes fp32 partial
// + resid (x1); z=1..3 write bf16 partials. 2 blocks/CU. ~674 TF = measured
// 2-phase structure ceiling (m248 class); dbuf (R9, -29%) and async-split
// (R12, -16%) both regress -> do not touch.
// ---------------------------------------------------------------------------
#define KPS_ 4096
__global__ __launch_bounds__(512, 4) void moe256(
    const u16* __restrict__ A, const u16* __restrict__ Bt,
    const float* __restrict__ gate, const float* __restrict__ resid,
    float* __restrict__ partF, u16* __restrict__ partB)
{
    __shared__ __align__(16) u16 lA[256][72];  // 36864 B
    __shared__ __align__(16) u16 lB[128][72];  // 18432 B
    const int t = threadIdx.x;
    const int lane = t & 63, wid = t >> 6;
    const int wr = wid >> 1, wc = wid & 1;      // wave -> 64-row, 64-col quadrant
    const int rowBase = blockIdx.x * 256;
    const int colBase = blockIdx.y * 128;
    const int z = blockIdx.z;
    const int eBase = z * (KPS_ / 512);         // 8 experts per split
    float* outF = (z == 0) ? partF : nullptr;
    u16* outB = (z == 0) ? nullptr : partB + (size_t)(z - 1) * M_ * D_;
    const int srow = t >> 3;        // 0..63
    const int scol = (t & 7) * 8;   // 0..56
    const int l15 = lane & 15;
    const int kreg = (lane >> 4) * 8;

    f32x4 acc[4][4] = {};

    for (int ei = 0; ei < 8; ++ei) {
        const int e = eBase + ei;
        float g[4];
#pragma unroll
        for (int i = 0; i < 4; ++i)
            g[i] = gate[(size_t)(rowBase + srow + 64 * i) * E_ + e];
#pragma unroll 1
        for (int k8 = 0; k8 < 8; ++k8) {
            const int akb = k8 * 64;
            const int kb = e * 512 + akb;
#pragma unroll
            for (int i = 0; i < 4; ++i) {
                int r = srow + 64 * i;
                bf16x8 raw = *(const bf16x8*)(A + (size_t)(rowBase + r) * 512 + akb + scol);
                bf16x8 o;
#pragma unroll
                for (int j = 0; j < 8; ++j)
                    o[j] = (__bf16)((float)raw[j] * g[i]);
                *(bf16x8*)(&lA[r][scol]) = o;
            }
#pragma unroll
            for (int i = 0; i < 2; ++i) {
                int r = srow + 64 * i;
                *(int4*)(&lB[r][scol]) =
                    *(const int4*)(Bt + (size_t)(colBase + r) * (E_ * 512) + kb + scol);
            }
            __syncthreads();
#pragma unroll
            for (int kk = 0; kk < 64; kk += 32) {
                const int ko = kk + kreg;
                bf16x8 af[4], bfr[4];
#pragma unroll
                for (int mi = 0; mi < 4; ++mi)
                    af[mi] = *(const bf16x8*)(&lA[wr * 64 + mi * 16 + l15][ko]);
#pragma unroll
                for (int ni = 0; ni < 4; ++ni)
                    bfr[ni] = *(const bf16x8*)(&lB[wc * 64 + ni * 16 + l15][ko]);
#pragma unroll
                for (int mi = 0; mi < 4; ++mi)
#pragma unroll
                    for (int ni = 0; ni < 4; ++ni)
                        acc[mi][ni] = __builtin_amdgcn_mfma_f32_16x16x32_bf16(
                            af[mi], bfr[ni], acc[mi][ni], 0, 0, 0);
            }
            __syncthreads();
        }
    }
    // epilogue: C/D layout col=lane&15, row=(lane>>4)*4+reg  [m89-verified]
#pragma unroll
    for (int mi = 0; mi < 4; ++mi)
#pragma unroll
        for (int ni = 0; ni < 4; ++ni)
#pragma unroll
            for (int r = 0; r < 4; ++r) {
                int grow = rowBase + wr * 64 + mi * 16 + (lane >> 4) * 4 + r;
                int gcol = colBase + wc * 64 + ni * 16 + l15;
                float v = acc[mi][ni][r];
                if (outF) {
                    v += resid[(size_t)grow * D_ + gcol];
                    outF[(size_t)grow * D_ + gcol] = v;
                } else {
                    outB[(size_t)grow * D_ + gcol] = f2bf(v);
                }
            }
}

// ---------------------------------------------------------------------------
// Fallback GEMM (reg-staged, 128x64 tile, 256 thr) for N=64 (kd).
// ---------------------------------------------------------------------------
__global__ __launch_bounds__(256) void gemm_bt(
    const u16* __restrict__ A, const u16* __restrict__ Bt,
    const float* __restrict__ bias, float* __restrict__ outF,
    u16* __restrict__ outB, int Ndim, int K)
{
    __shared__ __align__(16) u16 lA[128][72];
    __shared__ __align__(16) u16 lB[64][72];
    const int t = threadIdx.x;
    const int lane = t & 63, wid = t >> 6;
    const int rowBase = blockIdx.x * 128;
    const int colBase = blockIdx.y * 64;
    const int srow = t >> 3;
    const int skb = (t & 7) * 8;
    const int l15 = lane & 15;
    const int kreg = (lane >> 4) * 8;

    f32x4 accT[2][4] = {};

    for (int kb = 0; kb < K; kb += 64) {
#pragma unroll
        for (int i = 0; i < 4; ++i) {
            int r = srow + 32 * i;
            size_t grow = (size_t)(rowBase + r);
            *(int4*)(&lA[r][skb]) = *(const int4*)(A + grow * (size_t)K + kb + skb);
        }
#pragma unroll
        for (int i = 0; i < 2; ++i) {
            int n = srow + 32 * i;
            int gn = colBase + n;
            int4 v = {0, 0, 0, 0};
            if (gn < Ndim) v = *(const int4*)(Bt + (size_t)gn * K + kb + skb);
            *(int4*)(&lB[n][skb]) = v;
        }
        __syncthreads();
#pragma unroll
        for (int kk = 0; kk < 64; kk += 32) {
            const int ko = kk + kreg;
            bf16x8 af[2], bfr[4];
            af[0] = *(const bf16x8*)(&lA[wid * 32 + l15][ko]);
            af[1] = *(const bf16x8*)(&lA[wid * 32 + 16 + l15][ko]);
#pragma unroll
            for (int ni = 0; ni < 4; ++ni)
                bfr[ni] = *(const bf16x8*)(&lB[ni * 16 + l15][ko]);
#pragma unroll
            for (int mi = 0; mi < 2; ++mi)
#pragma unroll
                for (int ni = 0; ni < 4; ++ni)
                    accT[mi][ni] = __builtin_amdgcn_mfma_f32_16x16x32_bf16(
                        af[mi], bfr[ni], accT[mi][ni], 0, 0, 0);
        }
        __syncthreads();
    }
#pragma unroll
    for (int mi = 0; mi < 2; ++mi)
#pragma unroll
        for (int ni = 0; ni < 4; ++ni)
#pragma unroll
            for (int r = 0; r < 4; ++r) {
                int grow = rowBase + wid * 32 + mi * 16 + (lane >> 4) * 4 + r;
                int gcol = colBase + ni * 16 + l15;
                if (gcol < Ndim) {
                    float v = accT[mi][ni][r];
                    if (bias)  v += bias[gcol];
                    if (outF)  outF[(size_t)grow * Ndim + gcol] = v;
                    if (outB)  outB[(size_t)grow * Ndim + gcol] = f2bf(v);
                }
            }
}

// ---------------------------------------------------------------------------
// Gate fused: logits = h2 @ wgT + bg (MFMA, N=32), softmax over 32 in-register.
// ---------------------------------------------------------------------------
__global__ __launch_bounds__(256) void gatefused_k(
    const u16* __restrict__ A, const u16* __restrict__ Bt,
    const float* __restrict__ bg, float* __restrict__ gate)
{
    __shared__ __align__(16) u16 lA[128][72];
    __shared__ __align__(16) u16 lB[32][72];
    const int t = threadIdx.x;
    const int lane = t & 63, wid = t >> 6;
    const int rowBase = blockIdx.x * 128;
    const int srow = t >> 3;        // 0..31
    const int skb = (t & 7) * 8;
    const int l15 = lane & 15;
    const int kreg = (lane >> 4) * 8;

    f32x4 accT[2][2] = {};

    for (int kb = 0; kb < 512; kb += 64) {
#pragma unroll
        for (int i = 0; i < 4; ++i) {
            int r = srow + 32 * i;
            *(int4*)(&lA[r][skb]) =
                *(const int4*)(A + (size_t)(rowBase + r) * 512 + kb + skb);
        }
        *(int4*)(&lB[srow][skb]) = *(const int4*)(Bt + (size_t)srow * 512 + kb + skb);
        __syncthreads();
#pragma unroll
        for (int kk = 0; kk < 64; kk += 32) {
            const int ko = kk + kreg;
            bf16x8 af[2], bfr[2];
            af[0] = *(const bf16x8*)(&lA[wid * 32 + l15][ko]);
            af[1] = *(const bf16x8*)(&lA[wid * 32 + 16 + l15][ko]);
#pragma unroll
            for (int ni = 0; ni < 2; ++ni)
                bfr[ni] = *(const bf16x8*)(&lB[ni * 16 + l15][ko]);
#pragma unroll
            for (int mi = 0; mi < 2; ++mi)
#pragma unroll
                for (int ni = 0; ni < 2; ++ni)
                    accT[mi][ni] = __builtin_amdgcn_mfma_f32_16x16x32_bf16(
                        af[mi], bfr[ni], accT[mi][ni], 0, 0, 0);
        }
        __syncthreads();
    }
#pragma unroll
    for (int mi = 0; mi < 2; ++mi)
#pragma unroll
        for (int r = 0; r < 4; ++r) {
            float v0 = accT[mi][0][r] + bg[l15];
            float v1 = accT[mi][1][r] + bg[16 + l15];
            float m = fmaxf(v0, v1);
#pragma unroll
            for (int off = 1; off < 16; off <<= 1) m = fmaxf(m, __shfl_xor(m, off, 64));
            float p0 = __expf(v0 - m), p1 = __expf(v1 - m);
            float den = p0 + p1;
#pragma unroll
            for (int off = 1; off < 16; off <<= 1) den += __shfl_xor(den, off, 64);
            float rinv = 1.0f / den;
            int grow = rowBase + wid * 32 + mi * 16 + (lane >> 4) * 4 + r;
            gate[(size_t)grow * E_ + l15] = p0 * rinv;
            gate[(size_t)grow * E_ + 16 + l15] = p1 * rinv;
        }
}

// ---------------------------------------------------------------------------
// out = pF + bf(p1) + bf(p2) + bf(p3)   (pF fp32 already includes x1)
// ---------------------------------------------------------------------------
__global__ __launch_bounds__(256) void reduceP_k(
    const float* __restrict__ pf, const u16* __restrict__ pb,
    float* __restrict__ o, int n4)
{
    int i = blockIdx.x * 256 + threadIdx.x;
    const int stride = gridDim.x * 256;
    for (; i < n4; i += stride) {
        float4 v = ((const float4*)pf)[i];
#pragma unroll
        for (int s = 0; s < 3; ++s) {
            ushort4 u = ((const ushort4*)pb)[i + s * n4];
            v.x += bf2f(u.x); v.y += bf2f(u.y);
            v.z += bf2f(u.z); v.w += bf2f(u.w);
        }
        ((float4*)o)[i] = v;
    }
}

// ---------------------------------------------------------------------------
// Per-token attention across heads (bf16 q/kv): RoPE (table), 8x8 scores,
// softmax, PV. 4 tokens per 256-thr block, one wave per token.
// ---------------------------------------------------------------------------
__global__ __launch_bounds__(256) void attn_k(
    const u16* __restrict__ q, const u16* __restrict__ kv,
    const float2* __restrict__ rope, u16* __restrict__ out)
{
    const int wv = threadIdx.x >> 6;            // 0..3: token slot
    const int tok = blockIdx.x * 4 + wv;
    const int tpos = tok & (T_ - 1);
    const int l = threadIdx.x & 63;
    __shared__ float sq[4][8][65], sk[4][8][65], sv[4][8][65];
    __shared__ float satt[4][8][9];
    const int h = l >> 3;
    const int j0 = (l & 7) * 4;
    const u16* qr = q + (size_t)tok * 512;
    const u16* kr = kv + (size_t)tok * 1024;
#pragma unroll
    for (int jj = 0; jj < 4; ++jj) {
        int j = j0 + jj;
        float2 cssn = rope[tpos * 32 + j];
        float cs = cssn.x, sn = cssn.y;
        float q1 = bf2f(qr[h * 64 + j]), q2 = bf2f(qr[h * 64 + 32 + j]);
        sq[wv][h][j] = q1 * cs - q2 * sn;
        sq[wv][h][j + 32] = q1 * sn + q2 * cs;
        float k1 = bf2f(kr[h * 128 + j]), k2 = bf2f(kr[h * 128 + 32 + j]);
        sk[wv][h][j] = k1 * cs - k2 * sn;
        sk[wv][h][j + 32] = k1 * sn + k2 * cs;
        sv[wv][h][j] = bf2f(kr[h * 128 + 64 + j]);
        sv[wv][h][j + 32] = bf2f(kr[h * 128 + 96 + j]);
    }
    __syncthreads();
    const int g = l & 7;
    float s = 0.f;
#pragma unroll 8
    for (int c = 0; c < 64; ++c) s += sq[wv][h][c] * sk[wv][g][c];
    s *= 0.125f;
    float m = s;
#pragma unroll
    for (int off = 4; off; off >>= 1) m = fmaxf(m, __shfl_xor(m, off, 8));
    float p = __expf(s - m);
    float den = p;
#pragma unroll
    for (int off = 4; off; off >>= 1) den += __shfl_xor(den, off, 8);
    satt[wv][h][g] = p / den;
    __syncthreads();
    const int c8 = (l & 7) * 8;
    float o[8] = {};
#pragma unroll
    for (int gg = 0; gg < 8; ++gg) {
        float a = satt[wv][h][gg];
#pragma unroll
        for (int i = 0; i < 8; ++i) o[i] += a * sv[wv][gg][c8 + i];
    }
    int4 pk;
    pk.x = pack2(o[0], o[1]); pk.y = pack2(o[2], o[3]);
    pk.z = pack2(o[4], o[5]); pk.w = pack2(o[6], o[7]);
    *(int4*)(out + (size_t)tok * 512 + h * 64 + c8) = pk;
}

// ---------------------------------------------------------------------------
extern "C" void kernel_launch(void* const* d_in, const int* in_sizes, int n_in,
                              void* d_out, int out_size, void* d_ws, size_t ws_size,
                              hipStream_t stream)
{
    const float* x      = (const float*)d_in[0];
    const float* gamma1 = (const float*)d_in[1];
    const float* gamma2 = (const float*)d_in[2];
    const float* wq     = (const float*)d_in[3];
    const float* bq     = (const float*)d_in[4];
    const float* wkd    = (const float*)d_in[5];
    const float* bkd    = (const float*)d_in[6];
    const float* wku    = (const float*)d_in[7];
    const float* bku    = (const float*)d_in[8];
    const float* wo     = (const float*)d_in[9];
    const float* bo     = (const float*)d_in[10];
    const float* wg     = (const float*)d_in[11];
    const float* bg     = (const float*)d_in[12];
    const float* expw   = (const float*)d_in[13];

    char* w = (char*)d_ws;
    size_t off = 0;
    auto alloc = [&](size_t bytes) -> void* {
        void* p = w + off; off += (bytes + 255) & ~(size_t)255; return p;
    };
    u16*   h_b    = (u16*)alloc((size_t)M_ * D_ * 2);
    u16*   kd_b   = (u16*)alloc((size_t)M_ * DLAT_ * 2);
    u16*   at_b   = (u16*)alloc((size_t)M_ * D_ * 2);
    u16*   h2_b   = (u16*)alloc((size_t)M_ * D_ * 2);
    u16*   q_b    = (u16*)alloc((size_t)M_ * D_ * 2);
    u16*   kv_b   = (u16*)alloc((size_t)M_ * 2 * D_ * 2);
    float* partF  = (float*)alloc((size_t)M_ * D_ * 4);       // z=0 fp32 (+x1)
    u16*   partB  = (u16*)alloc((size_t)3 * M_ * D_ * 2);     // z=1..3 bf16
    float* x1_f   = (float*)alloc((size_t)M_ * D_ * 4);
    float* gate_f = (float*)alloc((size_t)M_ * E_ * 4);
    float2* rope_t = (float2*)alloc((size_t)T_ * 32 * 8);
    u16*   wqT    = (u16*)alloc((size_t)D_ * D_ * 2);
    u16*   wkdT   = (u16*)alloc((size_t)D_ * DLAT_ * 2);
    u16*   wkuT   = (u16*)alloc((size_t)DLAT_ * 2 * D_ * 2);
    u16*   woT    = (u16*)alloc((size_t)D_ * D_ * 2);
    u16*   wgT    = (u16*)alloc((size_t)D_ * E_ * 2);
    u16*   expT   = (u16*)alloc((size_t)E_ * D_ * D_ * 2);
    (void)ws_size; (void)in_sizes; (void)n_in; (void)out_size;

    // fused prep: all weight transposes + rope table (one launch, 9072 blocks)
    prep_k<<<9072, 256, 0, stream>>>(wq, wkd, wku, wo, wg, expw,
                                     wqT, wkdT, wkuT, woT, wgT, expT, rope_t);
    // h = rmsnorm(x, gamma1)  (bf16 only)
    rmsnorm_k<<<M_, 256, 0, stream>>>(x, gamma1, nullptr, h_b);
    // q = h @ wq + bq (bf16 out)
    gemm8w<<<dim3(64, 4), 512, 0, stream>>>(h_b, wqT, bq, nullptr, nullptr, q_b,
                                            512, 512, 512);
    // kd = h @ wkd + bkd (bf16 out)  -- N=64, fallback kernel
    gemm_bt<<<dim3(64, 1), 256, 0, stream>>>(h_b, wkdT, bkd, nullptr, kd_b, 64, 512);
    // kv = kd @ wku + bku (bf16 out)  -- K=64, single K-step
    gemm8w<<<dim3(64, 8), 512, 0, stream>>>(kd_b, wkuT, bku, nullptr, nullptr, kv_b,
                                            1024, 64, 64);
    // attention (rope + softmax over heads + PV), 4 tokens/block
    attn_k<<<M_ / 4, 256, 0, stream>>>(q_b, kv_b, rope_t, at_b);
    // x1 = x + attnout @ wo + bo (fp32 out)
    gemm8w<<<dim3(64, 4), 512, 0, stream>>>(at_b, woT, bo, x, x1_f, nullptr,
                                            512, 512, 512);
    // h2 = rmsnorm(x1, gamma2) (bf16 only)
    rmsnorm_k<<<M_, 256, 0, stream>>>(x1_f, gamma2, nullptr, h2_b);
    // gate = softmax(h2 @ wg + bg)  -- MFMA GEMM + fused in-register softmax
    gatefused_k<<<dim3(64, 1), 256, 0, stream>>>(h2_b, wgT, bg, gate_f);
    // moe partials: z=0 fp32 (+x1 resid), z=1..3 bf16
    moe256<<<dim3(32, 4, 4), 512, 0, stream>>>(h2_b, expT, gate_f, x1_f,
                                               partF, partB);
    // out = partF + sum of 3 bf16 partials
    reduceP_k<<<2048, 256, 0, stream>>>(partF, partB, (float*)d_out, M_ * D_ / 4);
}